// Round 12
// baseline (43.115 us; speedup 1.0000x reference)
//
#include <hip/hip_runtime.h>
#include <math.h>

// LogicConv2d, prep + barrier-minimal dataflow main.
//
// prep (1 block): softmax(sel_a), softmax(sel_b), collapse 16-way mix to
//   out = Cab*ab + Ca*a + Cb*b + C0. tab[81][24] floats in d_ws.
//
// main: 2048 blocks x 64 threads (ONE wave per block); lane <-> batch.
//   - in[81] loaded DIRECTLY from global, scalar per lane (stride 324 B
//     across lanes). A wave's footprint is 64x324 B = 20.7 KB = 162
//     contiguous lines -> fits L1; each line fetched once, ~30 L1 hits.
//     Reads need no coalescing in an L1/L3-resident regime — this deletes
//     the input LDS staging AND its vmcnt(0)+barrier phase entirely.
//   - All 81 units computed per lane, fully unrolled; weights via
//     wave-uniform scalar loads from d_ws (SGPR operands, free for VALU).
//   - Only writes need coalescing: results go through a 20.7 KB LDS
//     out-tile (scalar ds_write stride-81 = conflict-free), one wave-local
//     barrier, then coalesced float4 writeback.
//   7 independent single-wave blocks/CU, each free-running at its own
//   phase — no cross-wave lockstep anywhere.

#define NB      131072
#define NUNITS  81
#define THREADS 64
#define NBLK    (NB / THREADS)  // 2048
#define REC     24              // floats per unit record (96 B)
#define CHUNKS  (THREADS * 81 / 4) // 1296 float4 per out-tile

__global__ __launch_bounds__(256)
void logic_prep_kernel(const float* __restrict__ sa_logits,
                       const float* __restrict__ sb_logits,
                       const float* __restrict__ op_logits,
                       float* __restrict__ tab)
{
    const int tid = threadIdx.x;
    if (tid < 81) {
        const int u = tid;
        float v[9], m = -1e30f;
        #pragma unroll
        for (int i = 0; i < 9; ++i) { v[i] = sa_logits[u * 9 + i]; m = fmaxf(m, v[i]); }
        float s = 0.f;
        #pragma unroll
        for (int i = 0; i < 9; ++i) { v[i] = expf(v[i] - m); s += v[i]; }
        const float r = 1.f / s;
        #pragma unroll
        for (int i = 0; i < 9; ++i) tab[u * REC + i] = v[i] * r;
    } else if (tid < 162) {
        const int u = tid - 81;
        float v[9], m = -1e30f;
        #pragma unroll
        for (int i = 0; i < 9; ++i) { v[i] = sb_logits[u * 9 + i]; m = fmaxf(m, v[i]); }
        float s = 0.f;
        #pragma unroll
        for (int i = 0; i < 9; ++i) { v[i] = expf(v[i] - m); s += v[i]; }
        const float r = 1.f / s;
        #pragma unroll
        for (int i = 0; i < 9; ++i) tab[u * REC + 9 + i] = v[i] * r;
    } else if (tid < 243) {
        const int u = tid - 162;
        float v[16], m = -1e30f;
        #pragma unroll
        for (int i = 0; i < 16; ++i) { v[i] = op_logits[u * 16 + i]; m = fmaxf(m, v[i]); }
        float s = 0.f;
        #pragma unroll
        for (int i = 0; i < 16; ++i) { v[i] = expf(v[i] - m); s += v[i]; }
        const float r = 1.f / s;
        #pragma unroll
        for (int i = 0; i < 16; ++i) v[i] *= r;
        const float cab = v[1] - v[2] - v[4] - 2.f*v[6] - v[7] + v[8] + 2.f*v[9]
                        + v[11] + v[13] - v[14];
        const float ca  = v[2] + v[3] + v[6] + v[7] - v[8] - v[9] - v[12] - v[13];
        const float cb  = v[4] + v[5] + v[6] + v[7] - v[8] - v[9] - v[10] - v[11];
        const float c0  = v[8] + v[9] + v[10] + v[11] + v[12] + v[13] + v[14] + v[15];
        tab[u * REC + 18] = cab;
        tab[u * REC + 19] = ca;
        tab[u * REC + 20] = cb;
        tab[u * REC + 21] = c0;
    }
}

__global__ __launch_bounds__(THREADS, 2)
void logic_main_kernel(const float* __restrict__ x,
                       const float* __restrict__ tab,
                       float* __restrict__ out)
{
    __shared__ float s_out[THREADS * 81];   // 20736 B out-transpose tile

    const int lane  = threadIdx.x;          // one wave per block
    const size_t b  = (size_t)blockIdx.x * THREADS + lane;

    // ---- per-lane input row, straight from global (L1-absorbed) ----
    float in[81];
    {
        const float* __restrict__ src = x + b * 81;
        #pragma unroll
        for (int j = 0; j < 81; ++j) in[j] = src[j];
    }

    // ---- all 81 units, fully unrolled; weights via uniform s_loads ----
    float* my = s_out + lane * 81;          // stride 81: conflict-free
    #pragma unroll
    for (int u = 0; u < NUNITS; ++u) {
        const int p    = u / 9;                       // compile-time
        const int base = (p / 3) * 27 + (p % 3) * 3;  // row,col of patch
        const float* __restrict__ wr = tab + u * REC; // uniform -> SGPR
        float a = 0.f, bb = 0.f;
        #pragma unroll
        for (int i = 0; i < 9; ++i) {
            const float xi = in[base + (i / 3) * 9 + (i % 3)];
            a  = fmaf(xi, wr[i],     a);
            bb = fmaf(xi, wr[9 + i], bb);
        }
        my[u] = fmaf(wr[18], a * bb, fmaf(wr[19], a, fmaf(wr[20], bb, wr[21])));
    }

    __syncthreads();   // wave-local: flush LDS before transpose readback

    // ---- coalesced float4 writeback: 1296 chunks / 64 lanes ----
    {
        const float4* s4 = (const float4*)s_out;
        float4* gdst = (float4*)(out + (size_t)blockIdx.x * THREADS * 81);
        #pragma unroll
        for (int k = 0; k < 21; ++k) {
            const int j = k * THREADS + lane;
            if (j < CHUNKS) gdst[j] = s4[j];
        }
    }
}

extern "C" void kernel_launch(void* const* d_in, const int* in_sizes, int n_in,
                              void* d_out, int out_size, void* d_ws, size_t ws_size,
                              hipStream_t stream)
{
    const float* x  = (const float*)d_in[0];
    const float* sa = (const float*)d_in[1];
    const float* sb = (const float*)d_in[2];
    const float* op = (const float*)d_in[3];
    float* tab  = (float*)d_ws;             // 81*24*4 = 7776 B
    float* outp = (float*)d_out;

    logic_prep_kernel<<<1, 256, 0, stream>>>(sa, sb, op, tab);
    logic_main_kernel<<<NBLK, THREADS, 0, stream>>>(x, tab, outp);
}

// Round 13
// 27.068 us; speedup vs baseline: 1.5928x; 1.5928x over previous
//
#include <hip/hip_runtime.h>
#include <math.h>

// LogicConv2d, prep + PERSISTENT grid-stride main.
//
// prep (1 block): softmax(sel_a), softmax(sel_b), collapse 16-way mix to
//   out = Cab*ab + Ca*a + Cb*b + C0. tab[81][24] floats in d_ws, readable as
//   6 aligned float4 per unit: q0=sa[0:4] q1=sa[4:8] q2={sa8,sb0,sb1,sb2}
//   q3=sb[3:7] q4={sb7,sb8,Cab,Ca} q5={Cb,C0,-,-}.
//
// main: 1792 persistent blocks (7/CU = LDS residency limit) x 256 threads;
//   each loops tiles t = bid, bid+1792 (64 batches/tile). Body = R9's
//   proven-best: global_load_lds DMA staging; compute wave w<3 owns units
//   27w..27w+26 == patch-row w (27 inputs hoisted to regs; weights via
//   wave-uniform float4 loads, L2-hot; fully unrolled; in-place tile);
//   coalesced float4 writeback. Third barrier protects the LDS tile from
//   the next iteration's DMA (lgkm-cheap; the store drain folds into the
//   next stage-wait since stores are older in the in-order VMEM queue).
//   Rationale: R1-R12 show a 30 us plateau across 7 structures with ALL
//   pipes <25% busy — the shared unmeasured cost is per-replay dispatch
//   ramp/drain of 2048 short blocks. Persistence amortizes it.

#define NB      131072
#define NUNITS  81
#define BPB     64             // batches per tile
#define THREADS 256
#define NTILES  (NB / BPB)     // 2048
#define PBLK    1792           // persistent blocks = 7 per CU x 256 CUs
#define REC     24             // floats per unit record (96 B)
#define CHUNKS  (BPB * 81 / 4) // 1296 float4 per tile

typedef __attribute__((address_space(1))) const void GAS;
typedef __attribute__((address_space(3))) void LAS;

__global__ __launch_bounds__(256)
void logic_prep_kernel(const float* __restrict__ sa_logits,
                       const float* __restrict__ sb_logits,
                       const float* __restrict__ op_logits,
                       float* __restrict__ tab)
{
    const int tid = threadIdx.x;
    if (tid < 81) {
        const int u = tid;
        float v[9], m = -1e30f;
        #pragma unroll
        for (int i = 0; i < 9; ++i) { v[i] = sa_logits[u * 9 + i]; m = fmaxf(m, v[i]); }
        float s = 0.f;
        #pragma unroll
        for (int i = 0; i < 9; ++i) { v[i] = expf(v[i] - m); s += v[i]; }
        const float r = 1.f / s;
        #pragma unroll
        for (int i = 0; i < 9; ++i) tab[u * REC + i] = v[i] * r;
    } else if (tid < 162) {
        const int u = tid - 81;
        float v[9], m = -1e30f;
        #pragma unroll
        for (int i = 0; i < 9; ++i) { v[i] = sb_logits[u * 9 + i]; m = fmaxf(m, v[i]); }
        float s = 0.f;
        #pragma unroll
        for (int i = 0; i < 9; ++i) { v[i] = expf(v[i] - m); s += v[i]; }
        const float r = 1.f / s;
        #pragma unroll
        for (int i = 0; i < 9; ++i) tab[u * REC + 9 + i] = v[i] * r;
    } else if (tid < 243) {
        const int u = tid - 162;
        float v[16], m = -1e30f;
        #pragma unroll
        for (int i = 0; i < 16; ++i) { v[i] = op_logits[u * 16 + i]; m = fmaxf(m, v[i]); }
        float s = 0.f;
        #pragma unroll
        for (int i = 0; i < 16; ++i) { v[i] = expf(v[i] - m); s += v[i]; }
        const float r = 1.f / s;
        #pragma unroll
        for (int i = 0; i < 16; ++i) v[i] *= r;
        const float cab = v[1] - v[2] - v[4] - 2.f*v[6] - v[7] + v[8] + 2.f*v[9]
                        + v[11] + v[13] - v[14];
        const float ca  = v[2] + v[3] + v[6] + v[7] - v[8] - v[9] - v[12] - v[13];
        const float cb  = v[4] + v[5] + v[6] + v[7] - v[8] - v[9] - v[10] - v[11];
        const float c0  = v[8] + v[9] + v[10] + v[11] + v[12] + v[13] + v[14] + v[15];
        tab[u * REC + 18] = cab;
        tab[u * REC + 19] = ca;
        tab[u * REC + 20] = cb;
        tab[u * REC + 21] = c0;
    }
}

__global__ __launch_bounds__(THREADS, 7)
void logic_main_kernel(const float* __restrict__ x,
                       const float* __restrict__ tab,
                       float* __restrict__ out)
{
    __shared__ float s_tile[BPB * 81];     // 20736 B — the only LDS

    const int tid   = threadIdx.x;
    const int lane  = tid & 63;
    const int wavei = __builtin_amdgcn_readfirstlane(tid >> 6);

    for (int t = blockIdx.x; t < NTILES; t += PBLK) {
        const size_t b0 = (size_t)t * BPB;

        // ---- stage input tile via global->LDS DMA ----
        {
            const float4* gsrc = (const float4*)(x + b0 * 81);
            #pragma unroll
            for (int k = 0; k < 6; ++k) {
                const int j = tid + k * THREADS;
                if (j < CHUNKS) {
                    // wave-uniform LDS base; hardware adds lane*16
                    float* lbase = s_tile + (size_t)(k * THREADS + wavei * 64) * 4;
                    __builtin_amdgcn_global_load_lds((GAS*)(gsrc + j), (LAS*)lbase,
                                                     16, 0, 0);
                }
            }
        }
        __syncthreads();

        // ---- compute: wave w<3 owns units 27w..27w+26 (== patch-row w) ----
        if (wavei < 3) {
            float* my = s_tile + lane * 81 + wavei * 27;    // read == write slice

            float in[27];                                    // img rows 3w..3w+2
            #pragma unroll
            for (int j = 0; j < 27; ++j) in[j] = my[j];

            const float4* __restrict__ wt4 =
                (const float4*)(tab + (size_t)wavei * 27 * REC);  // uniform base

            #pragma unroll
            for (int j = 0; j < 27; ++j) {                   // unit u = 27*wavei+j
                const int q = j / 9;                         // patch col within row
                const float4 q0 = wt4[j * 6 + 0];
                const float4 q1 = wt4[j * 6 + 1];
                const float4 q2 = wt4[j * 6 + 2];
                const float4 q3 = wt4[j * 6 + 3];
                const float4 q4 = wt4[j * 6 + 4];
                const float4 q5 = wt4[j * 6 + 5];
                const float wa[9] = { q0.x, q0.y, q0.z, q0.w, q1.x, q1.y, q1.z, q1.w, q2.x };
                const float wb[9] = { q2.y, q2.z, q2.w, q3.x, q3.y, q3.z, q3.w, q4.x, q4.y };
                float a = 0.f, b = 0.f;
                #pragma unroll
                for (int i = 0; i < 9; ++i) {
                    const float xi = in[q * 3 + (i / 3) * 9 + (i % 3)];
                    a = fmaf(xi, wa[i], a);
                    b = fmaf(xi, wb[i], b);
                }
                // q4.z=Cab q4.w=Ca q5.x=Cb q5.y=C0
                my[j] = fmaf(q4.z, a * b, fmaf(q4.w, a, fmaf(q5.x, b, q5.y)));
            }
        }

        __syncthreads();

        // ---- coalesced writeback, all 4 waves ----
        {
            const float4* s4 = (const float4*)s_tile;
            float4* gdst = (float4*)(out + b0 * 81);
            #pragma unroll
            for (int k = 0; k < 6; ++k) {
                const int j = tid + k * THREADS;
                if (j < CHUNKS) gdst[j] = s4[j];
            }
        }

        // protect LDS tile from next iteration's DMA (writeback's ds_reads
        // must complete; store drain folds into the next stage barrier)
        __syncthreads();
    }
}

extern "C" void kernel_launch(void* const* d_in, const int* in_sizes, int n_in,
                              void* d_out, int out_size, void* d_ws, size_t ws_size,
                              hipStream_t stream)
{
    const float* x  = (const float*)d_in[0];
    const float* sa = (const float*)d_in[1];
    const float* sb = (const float*)d_in[2];
    const float* op = (const float*)d_in[3];
    float* tab  = (float*)d_ws;             // 81*24*4 = 7776 B
    float* outp = (float*)d_out;

    logic_prep_kernel<<<1, 256, 0, stream>>>(sa, sb, op, tab);
    logic_main_kernel<<<PBLK, THREADS, 0, stream>>>(x, tab, outp);
}